// Round 8
// baseline (101.987 us; speedup 1.0000x reference)
//
#include <hip/hip_runtime.h>
#include <hip/hip_bf16.h>

typedef __attribute__((ext_vector_type(4)))  float f32x4;
typedef __attribute__((ext_vector_type(16))) float f32x16;
typedef __attribute__((ext_vector_type(8)))  short s16x8;
typedef __attribute__((ext_vector_type(4)))  short s16x4;
typedef __attribute__((ext_vector_type(4)))  int   i32x4;

#define BB 2
#define HH 8
#define SS 2048
#define DD 64
#define QBLK 64
#define KBLK 64
#define NT   (SS / KBLK)      // 32
#define NBH  (BB * HH)        // 16

// ws layout: K = per-(bh,kt) 8KB swizzled row-major images (LDS-staged);
//            V = per-(bh,kt,ks,dt,ch) 1KB frag-major blocks (read direct).
#define WS_KX 0
#define WS_KY ((size_t)NBH * NT * 8192)          // 4 MiB each
#define WS_VX ((size_t)2 * NBH * NT * 8192)
#define WS_VY ((size_t)3 * NBH * NT * 8192)
#define WS_NEED ((size_t)4 * NBH * NT * 8192)    // 16 MiB

// fp32 -> bf16 round-to-nearest-even
__device__ __forceinline__ short f2bf(float x) {
    unsigned u = __builtin_bit_cast(unsigned, x);
    u = (u + 0x7FFFu + ((u >> 16) & 1u)) >> 16;
    return (short)u;
}

// pack two f32 -> one dword of 2 bf16 (RNE)
__device__ __forceinline__ unsigned cvtpk(float lo, float hi) {
    unsigned d;
    asm("v_cvt_pk_bf16_f32 %0, %1, %2" : "=v"(d) : "v"(lo), "v"(hi));
    return d;
}

// XOR swizzle within a 128-byte row (guide G4) — K images only
__device__ __forceinline__ int swz(int row, int byteInRow) {
    return row * 128 + (byteInRow ^ ((row & 7) << 4));
}

// 16-byte async global->LDS copy
__device__ __forceinline__ void glds16(const void* g, void* l) {
    __builtin_amdgcn_global_load_lds(
        (const __attribute__((address_space(1))) unsigned*)g,
        (__attribute__((address_space(3))) unsigned*)l, 16, 0, 0);
}

// ------------- fused prepass: K row-major swizzled / V frag-major ------------
__global__ __launch_bounds__(256)
void prep_kv(const float* __restrict__ Kx, const float* __restrict__ Ky,
             const float* __restrict__ Vx, const float* __restrict__ Vy,
             char* __restrict__ ws)
{
    const int b = blockIdx.x;
    if (b < 1024) {
        const int tid  = b * 256 + threadIdx.x;
        const int dblk = tid & 7;
        const int s    = (tid >> 3) & 2047;
        const int bh   = tid >> 14;
        const size_t gi = ((size_t)bh * SS + s) * DD + dblk * 8;
        const int kt = s >> 6, row = s & 63;
        const size_t dst = (size_t)(bh * NT + kt) * 8192 + swz(row, dblk * 16);
        const float* px = Kx + gi;
        const float* py = Ky + gi;
        s16x8 a, bb;
#pragma unroll
        for (int i = 0; i < 8; ++i) { a[i] = f2bf(px[i]); bb[i] = f2bf(py[i]); }
        *(s16x8*)(ws + WS_KX + dst) = a;
        *(s16x8*)(ws + WS_KY + dst) = bb;
    } else {
        // V frag-major: elem e of lane (hi*32+l31) of frag (kt,ks,dt,ch) is
        // V[key = kt*64 + ks*32 + ch*16 + hi*8 + e][d = dt*32 + l31]
        const int tid  = (b - 1024) * 256 + threadIdx.x;
        const int d    = tid & 63;
        const int sblk = (tid >> 6) & 7;     // key octet within 64-key tile
        const int kt   = (tid >> 9) & 31;
        const int bh   = tid >> 14;
        const size_t gbase = ((size_t)bh * SS + kt * 64 + sblk * 8) * DD + d;
        s16x8 a, bb;
#pragma unroll
        for (int i = 0; i < 8; ++i) {
            a[i]  = f2bf(Vx[gbase + (size_t)i * DD]);
            bb[i] = f2bf(Vy[gbase + (size_t)i * DD]);
        }
        const int ks = sblk >> 2, ch = (sblk >> 1) & 1, hi = sblk & 1;
        const int dt = d >> 5, l31 = d & 31;
        const size_t dst = (size_t)bh * 262144
                         + (size_t)((((kt * 2 + ks) * 2 + dt) * 2 + ch)) * 1024
                         + (size_t)(hi * 32 + l31) * 16;
        *(s16x8*)(ws + WS_VX + dst) = a;
        *(s16x8*)(ws + WS_VY + dst) = bb;
    }
}

// ------------------------------- main kernel ---------------------------------
// 32x32x16 MFMA, swapped QK^T, in-register softmax (no max; scores bounded).
// 4 waves = qsub(2: 32 q-rows) x ks(2: 32-key half). QBLK=64, grid 512.
// K: LDS double-buffer (2 x 16KB) via global_load_lds.
// V: loaded DIRECTLY from frag-major ws (L1/L2-resident; no LDS round-trip).
// LDS 32KB -> up to 4 blocks/CU; target 4 waves/SIMD (16 waves/CU), no
// duplicated work (R7 lesson: d-split duplication cost more than occupancy won).
__global__ __launch_bounds__(256, 4)
void attn_main(const float* __restrict__ Qx, const float* __restrict__ Qy,
               const char* __restrict__ ws, float* __restrict__ Out)
{
    extern __shared__ char lds[];

    const int t    = threadIdx.x;
    const int lane = t & 63;
    const int w    = t >> 6;      // 0..3
    const int qsub = w & 1;
    const int ks   = w >> 1;
    const int l31  = lane & 31;
    const int hi   = lane >> 5;   // 0/1

    // XCD-chunked swizzle (512 % 8 == 0, bijective): 64 consecutive per XCD
    int bid = blockIdx.x;
    bid = (bid & 7) * 64 + (bid >> 3);
    const int bh = bid >> 5;
    const int q0 = (bid & 31) * QBLK;
    const size_t base = (size_t)bh * SS * DD;

    // ---- Q B-frags: col q = lane&31, k = d = dc*16 + hi*8 + i
    const int qrow = q0 + qsub * 32 + l31;
    s16x8 qbx[4], qby[4];
#pragma unroll
    for (int dc = 0; dc < 4; ++dc) {
        const int d0 = dc * 16 + hi * 8;
        const float* qp = Qx + base + (size_t)qrow * DD + d0;
        const float* qq = Qy + base + (size_t)qrow * DD + d0;
        const float4 f0 = *(const float4*)qp;
        const float4 f1 = *(const float4*)(qp + 4);
        const float4 h0 = *(const float4*)qq;
        const float4 h1 = *(const float4*)(qq + 4);
        qbx[dc][0]=f2bf(f0.x); qbx[dc][1]=f2bf(f0.y); qbx[dc][2]=f2bf(f0.z); qbx[dc][3]=f2bf(f0.w);
        qbx[dc][4]=f2bf(f1.x); qbx[dc][5]=f2bf(f1.y); qbx[dc][6]=f2bf(f1.z); qbx[dc][7]=f2bf(f1.w);
        qby[dc][0]=f2bf(h0.x); qby[dc][1]=f2bf(h0.y); qby[dc][2]=f2bf(h0.z); qby[dc][3]=f2bf(h0.w);
        qby[dc][4]=f2bf(h1.x); qby[dc][5]=f2bf(h1.y); qby[dc][6]=f2bf(h1.z); qby[dc][7]=f2bf(h1.w);
    }

    f32x16 o1_0, o1_1, o2_0, o2_1;
#pragma unroll
    for (int j = 0; j < 16; ++j) { o1_0[j] = 0.f; o1_1[j] = 0.f; o2_0[j] = 0.f; o2_1[j] = 0.f; }
    float lsum = 0.f;

    const float SCL = 0.09016844005556021f;   // log2(e) / (2*sqrt(64))

    // stage K tile kt_ into buffer b_ (4 x glds16 per thread; 256 thr)
#define STAGE(kt_, b_)                                                             \
    do {                                                                           \
        const size_t img_ = (size_t)(bh * NT + (kt_)) * 8192 + (size_t)t * 16;     \
        char* dst_ = lds + (b_) * 16384 + t * 16;                                  \
        glds16(ws + WS_KX + img_,        dst_);                                    \
        glds16(ws + WS_KX + img_ + 4096, dst_ + 4096);                             \
        glds16(ws + WS_KY + img_,        dst_ + 8192);                             \
        glds16(ws + WS_KY + img_ + 4096, dst_ + 12288);                            \
    } while (0)

    STAGE(0, 0);
    __syncthreads();
    int cur = 0;

    const char* vxb = ws + WS_VX + (size_t)bh * 262144 + (size_t)lane * 16;
    const char* vyb = ws + WS_VY + (size_t)bh * 262144 + (size_t)lane * 16;

    for (int kt = 0; kt < NT; ++kt) {
        if (kt + 1 < NT) STAGE(kt + 1, cur ^ 1);

        const char* KxL = lds + cur * 16384;
        const char* KyL = KxL + 8192;

        // ---- swapped scores: sc[key=crow(j,hi)][q=l31], keys = ks*32..+31
        f32x16 sc;
#pragma unroll
        for (int j = 0; j < 16; ++j) sc[j] = 0.f;
        __builtin_amdgcn_s_setprio(1);
#pragma unroll
        for (int dc = 0; dc < 4; ++dc) {
            const int off = swz(ks * 32 + l31, dc * 32 + hi * 16);
            const s16x8 ka = *(const s16x8*)(KxL + off);
            const s16x8 kb = *(const s16x8*)(KyL + off);
            sc = __builtin_amdgcn_mfma_f32_32x32x16_bf16(ka, qbx[dc], sc, 0, 0, 0);
            sc = __builtin_amdgcn_mfma_f32_32x32x16_bf16(kb, qby[dc], sc, 0, 0, 0);
        }
        __builtin_amdgcn_s_setprio(0);

        // ---- V frag loads (direct from ws; independent, issue early)
        const size_t vb = ((size_t)(kt * 2 + ks)) << 12;   // + dt*2048 + ch*1024
        const s16x8 vx00 = *(const s16x8*)(vxb + vb);
        const s16x8 vx01 = *(const s16x8*)(vxb + vb + 1024);
        const s16x8 vy00 = *(const s16x8*)(vyb + vb);
        const s16x8 vy01 = *(const s16x8*)(vyb + vb + 1024);

        // ---- softmax terms in place (|sc*SCL| <~ 30, fp32-safe without max)
        float s = 0.f;
#pragma unroll
        for (int j = 0; j < 16; ++j) {
            sc[j] = exp2f(sc[j] * SCL);
            s += sc[j];
        }
        lsum += s;

        // ---- P -> bf16 A-frags (R4-verified shfl_xor redistribution)
        s16x8 pa[2];
#pragma unroll
        for (int ch = 0; ch < 2; ++ch) {
            const int b8 = ch * 8;
            const unsigned x0 = cvtpk(sc[b8 + 0], sc[b8 + 1]);
            const unsigned x1 = cvtpk(sc[b8 + 2], sc[b8 + 3]);
            const unsigned y0 = cvtpk(sc[b8 + 4], sc[b8 + 5]);
            const unsigned y1 = cvtpk(sc[b8 + 6], sc[b8 + 7]);
            const unsigned xs0 = (unsigned)__shfl_xor((int)x0, 32);
            const unsigned xs1 = (unsigned)__shfl_xor((int)x1, 32);
            const unsigned ys0 = (unsigned)__shfl_xor((int)y0, 32);
            const unsigned ys1 = (unsigned)__shfl_xor((int)y1, 32);
            i32x4 pw;
            pw[0] = (int)(hi ? ys0 : x0);
            pw[1] = (int)(hi ? ys1 : x1);
            pw[2] = (int)(hi ? y0 : xs0);
            pw[3] = (int)(hi ? y1 : xs1);
            pa[ch] = __builtin_bit_cast(s16x8, pw);
        }

        // ---- PV: out[q=crow][d=dt*32+l31] += P * V  (dt1 frags loaded JIT)
        __builtin_amdgcn_s_setprio(1);
        o1_0 = __builtin_amdgcn_mfma_f32_32x32x16_bf16(pa[0], vx00, o1_0, 0, 0, 0);
        o1_0 = __builtin_amdgcn_mfma_f32_32x32x16_bf16(pa[1], vx01, o1_0, 0, 0, 0);
        o2_0 = __builtin_amdgcn_mfma_f32_32x32x16_bf16(pa[0], vy00, o2_0, 0, 0, 0);
        o2_0 = __builtin_amdgcn_mfma_f32_32x32x16_bf16(pa[1], vy01, o2_0, 0, 0, 0);
        {
            const s16x8 vx10 = *(const s16x8*)(vxb + vb + 2048);
            const s16x8 vx11 = *(const s16x8*)(vxb + vb + 3072);
            const s16x8 vy10 = *(const s16x8*)(vyb + vb + 2048);
            const s16x8 vy11 = *(const s16x8*)(vyb + vb + 3072);
            o1_1 = __builtin_amdgcn_mfma_f32_32x32x16_bf16(pa[0], vx10, o1_1, 0, 0, 0);
            o1_1 = __builtin_amdgcn_mfma_f32_32x32x16_bf16(pa[1], vx11, o1_1, 0, 0, 0);
            o2_1 = __builtin_amdgcn_mfma_f32_32x32x16_bf16(pa[0], vy10, o2_1, 0, 0, 0);
            o2_1 = __builtin_amdgcn_mfma_f32_32x32x16_bf16(pa[1], vy11, o2_1, 0, 0, 0);
        }
        __builtin_amdgcn_s_setprio(0);

        __syncthreads();    // next K buffer staged (vmcnt drained); cur reads done
        cur ^= 1;
    }
#undef STAGE

    // ---- epilogue: combine ks partials (two phases), per-q-row inverse, store
    const float lh = lsum + __shfl_xor(lsum, 32);   // 32-key-half sum for q=l31

    float* ex   = (float*)lds;                       // loop done: LDS reusable
    float* linv = (float*)(lds + 24576);             // 64 per-q-row inverses
    const int exo = (qsub * 64 + lane) * 33;         // stride 33: odd, conflict-lite
    float* O1 = Out;
    float* O2 = Out + (size_t)BB * HH * SS * DD;

    // phase 1: tensor X
    if (ks == 1) {
#pragma unroll
        for (int j = 0; j < 16; ++j) { ex[exo + j] = o1_0[j]; ex[exo + 16 + j] = o1_1[j]; }
        ex[exo + 32] = lh;
    }
    __syncthreads();
    if (ks == 0 && hi == 0)
        linv[qsub * 32 + l31] = 1.0f / (lh + ex[exo + 32]);
    __syncthreads();
    if (ks == 0) {
#pragma unroll
        for (int j = 0; j < 16; ++j) {
            const int qr = (j & 3) + 8 * (j >> 2) + 4 * hi;   // output q-row of reg j
            const float invj = linv[qsub * 32 + qr];
            const size_t ob = base + (size_t)(q0 + qsub * 32 + qr) * DD + l31;
            O1[ob]      = (o1_0[j] + ex[exo + j])      * invj;
            O1[ob + 32] = (o1_1[j] + ex[exo + 16 + j]) * invj;
        }
    }
    __syncthreads();
    // phase 2: tensor Y
    if (ks == 1) {
#pragma unroll
        for (int j = 0; j < 16; ++j) { ex[exo + j] = o2_0[j]; ex[exo + 16 + j] = o2_1[j]; }
    }
    __syncthreads();
    if (ks == 0) {
#pragma unroll
        for (int j = 0; j < 16; ++j) {
            const int qr = (j & 3) + 8 * (j >> 2) + 4 * hi;
            const float invj = linv[qsub * 32 + qr];
            const size_t ob = base + (size_t)(q0 + qsub * 32 + qr) * DD + l31;
            O2[ob]      = (o2_0[j] + ex[exo + j])      * invj;
            O2[ob + 32] = (o2_1[j] + ex[exo + 16 + j]) * invj;
        }
    }
}

// ===================== fallback (ws too small; validated R1 path) ============
__global__ __launch_bounds__(256, 2)
void attn_dual_fallback(const float* __restrict__ Qx, const float* __restrict__ Kx,
                        const float* __restrict__ Vx, const float* __restrict__ Qy,
                        const float* __restrict__ Ky, const float* __restrict__ Vy,
                        float* __restrict__ Out)
{
    __shared__ __attribute__((aligned(16))) char lds[40960];
    char* KxL  = lds;
    char* KyL  = lds + 8192;
    char* VtxL = lds + 16384;
    char* VtyL = lds + 24576;

    const int t    = threadIdx.x;
    const int lane = t & 63;
    const int w    = t >> 6;
    const int g    = lane >> 4;
    const int c    = lane & 15;
    char* PL = lds + 32768 + w * 2048;

    const int bid = blockIdx.x;
    const int bh  = bid >> 5;
    const int q0  = (bid & 31) * 64;
    const size_t base = (size_t)bh * SS * DD;

    const int qrowA = q0 + w * 16 + c;
    s16x8 qxf[2], qyf[2];
#pragma unroll
    for (int kk = 0; kk < 2; ++kk) {
        const int d0 = kk * 32 + g * 8;
        const float* qp = Qx + base + (size_t)qrowA * DD + d0;
        const float* qq = Qy + base + (size_t)qrowA * DD + d0;
#pragma unroll
        for (int i = 0; i < 8; ++i) { qxf[kk][i] = f2bf(qp[i]); qyf[kk][i] = f2bf(qq[i]); }
    }

    f32x4 o1[4], o2[4];
#pragma unroll
    for (int n = 0; n < 4; ++n) {
        o1[n] = (f32x4){0.f, 0.f, 0.f, 0.f};
        o2[n] = (f32x4){0.f, 0.f, 0.f, 0.f};
    }
    float m[4]    = {-1e30f, -1e30f, -1e30f, -1e30f};
    float lsum[4] = {0.f, 0.f, 0.f, 0.f};
    const float SCL = 0.09016844005556021f;

    for (int kt = 0; kt < SS / 64; ++kt) {
        __syncthreads();
#pragma unroll
        for (int j = 0; j < 4; ++j) {
            const int f   = t + 256 * j;
            const int row = f >> 4;
            const int c4  = f & 15;
            const size_t gi = base + (size_t)(kt * 64 + row) * DD + c4 * 4;
            const float4 kx = *(const float4*)(Kx + gi);
            const float4 ky = *(const float4*)(Ky + gi);
            const float4 vx = *(const float4*)(Vx + gi);
            const float4 vy = *(const float4*)(Vy + gi);
            s16x4 a; a[0]=f2bf(kx.x); a[1]=f2bf(kx.y); a[2]=f2bf(kx.z); a[3]=f2bf(kx.w);
            *(s16x4*)(KxL + swz(row, c4 * 8)) = a;
            s16x4 b; b[0]=f2bf(ky.x); b[1]=f2bf(ky.y); b[2]=f2bf(ky.z); b[3]=f2bf(ky.w);
            *(s16x4*)(KyL + swz(row, c4 * 8)) = b;
            const int d0 = c4 * 4;
            *(short*)(VtxL + swz(d0 + 0, row * 2)) = f2bf(vx.x);
            *(short*)(VtxL + swz(d0 + 1, row * 2)) = f2bf(vx.y);
            *(short*)(VtxL + swz(d0 + 2, row * 2)) = f2bf(vx.z);
            *(short*)(VtxL + swz(d0 + 3, row * 2)) = f2bf(vx.w);
            *(short*)(VtyL + swz(d0 + 0, row * 2)) = f2bf(vy.x);
            *(short*)(VtyL + swz(d0 + 1, row * 2)) = f2bf(vy.y);
            *(short*)(VtyL + swz(d0 + 2, row * 2)) = f2bf(vy.z);
            *(short*)(VtyL + swz(d0 + 3, row * 2)) = f2bf(vy.w);
        }
        __syncthreads();

        f32x4 sc[4];
#pragma unroll
        for (int n = 0; n < 4; ++n) {
            f32x4 acc = (f32x4){0.f, 0.f, 0.f, 0.f};
            const int keyrow = n * 16 + c;
#pragma unroll
            for (int kk = 0; kk < 2; ++kk) {
                const int off = swz(keyrow, (kk * 32 + g * 8) * 2);
                const s16x8 kxf = *(const s16x8*)(KxL + off);
                const s16x8 kyf = *(const s16x8*)(KyL + off);
                acc = __builtin_amdgcn_mfma_f32_16x16x32_bf16(qxf[kk], kxf, acc, 0, 0, 0);
                acc = __builtin_amdgcn_mfma_f32_16x16x32_bf16(qyf[kk], kyf, acc, 0, 0, 0);
            }
            sc[n] = acc;
        }

#pragma unroll
        for (int r = 0; r < 4; ++r) {
            float v0 = fmaxf(fmaxf(sc[0][r], sc[1][r]), fmaxf(sc[2][r], sc[3][r])) * SCL;
#pragma unroll
            for (int off = 1; off < 16; off <<= 1) v0 = fmaxf(v0, __shfl_xor(v0, off));
            const float mnew = fmaxf(m[r], v0);
            const float cr = exp2f(m[r] - mnew);
            m[r] = mnew;
            float srow = 0.f;
#pragma unroll
            for (int n = 0; n < 4; ++n) {
                const float pp = exp2f(sc[n][r] * SCL - mnew);
                srow += pp;
                *(short*)(PL + swz(g * 4 + r, (n * 16 + c) * 2)) = f2bf(pp);
            }
#pragma unroll
            for (int off = 1; off < 16; off <<= 1) srow += __shfl_xor(srow, off);
            lsum[r] = lsum[r] * cr + srow;
#pragma unroll
            for (int n = 0; n < 4; ++n) { o1[n][r] *= cr; o2[n][r] *= cr; }
        }

        s16x8 pf[2];
#pragma unroll
        for (int kk = 0; kk < 2; ++kk)
            pf[kk] = *(const s16x8*)(PL + swz(c, (kk * 32 + g * 8) * 2));
#pragma unroll
        for (int nd = 0; nd < 4; ++nd) {
            const int drow = nd * 16 + c;
#pragma unroll
            for (int kk = 0; kk < 2; ++kk) {
                const int off = swz(drow, (kk * 32 + g * 8) * 2);
                const s16x8 vxf = *(const s16x8*)(VtxL + off);
                const s16x8 vyf = *(const s16x8*)(VtyL + off);
                o1[nd] = __builtin_amdgcn_mfma_f32_16x16x32_bf16(pf[kk], vxf, o1[nd], 0, 0, 0);
                o2[nd] = __builtin_amdgcn_mfma_f32_16x16x32_bf16(pf[kk], vyf, o2[nd], 0, 0, 0);
            }
        }
    }

    float* O1 = Out;
    float* O2 = Out + (size_t)BB * HH * SS * DD;
#pragma unroll
    for (int r = 0; r < 4; ++r) {
        const float inv = 1.0f / lsum[r];
        const int qrow = q0 + w * 16 + g * 4 + r;
        const size_t ob = base + (size_t)qrow * DD + c;
#pragma unroll
        for (int nd = 0; nd < 4; ++nd) {
            O1[ob + nd * 16] = o1[nd][r] * inv;
            O2[ob + nd * 16] = o2[nd][r] * inv;
        }
    }
}

extern "C" void kernel_launch(void* const* d_in, const int* in_sizes, int n_in,
                              void* d_out, int out_size, void* d_ws, size_t ws_size,
                              hipStream_t stream) {
    const float* Qx = (const float*)d_in[0];
    const float* Kx = (const float*)d_in[1];
    const float* Vx = (const float*)d_in[2];
    const float* Qy = (const float*)d_in[3];
    const float* Ky = (const float*)d_in[4];
    const float* Vy = (const float*)d_in[5];
    float* Out = (float*)d_out;

    if (ws_size >= WS_NEED) {
        char* ws = (char*)d_ws;
        hipLaunchKernelGGL(prep_kv, dim3(2048), dim3(256), 0, stream,
                           Kx, Ky, Vx, Vy, ws);
        hipFuncSetAttribute((const void*)attn_main,
                            hipFuncAttributeMaxDynamicSharedMemorySize, 32768);
        hipLaunchKernelGGL(attn_main, dim3(NBH * (SS / QBLK)), dim3(256), 32768,
                           stream, Qx, Qy, (const char*)ws, Out);
    } else {
        hipLaunchKernelGGL(attn_dual_fallback, dim3(NBH * 32), dim3(256),
                           0, stream, Qx, Kx, Vx, Qy, Ky, Vy, Out);
    }
}

// Round 9
// 95.081 us; speedup vs baseline: 1.0726x; 1.0726x over previous
//
#include <hip/hip_runtime.h>
#include <hip/hip_bf16.h>

typedef __attribute__((ext_vector_type(4)))  float f32x4;
typedef __attribute__((ext_vector_type(16))) float f32x16;
typedef __attribute__((ext_vector_type(8)))  short s16x8;
typedef __attribute__((ext_vector_type(4)))  short s16x4;
typedef __attribute__((ext_vector_type(4)))  int   i32x4;

#define BB 2
#define HH 8
#define SS 2048
#define DD 64
#define QBLK 64
#define NT   32               // 64-key tiles (ws image granularity)
#define NT2  16               // 128-key tiles (main-loop granularity)
#define NBH  (BB * HH)        // 16

// ws layout: K = per-(bh,kt64) 8KB swizzled row-major images (LDS-staged);
//            V = per-(bh,kt64,ks2,dt,ch) 1KB frag-major blocks (read direct).
#define WS_KX 0
#define WS_KY ((size_t)NBH * NT * 8192)          // 4 MiB each
#define WS_VX ((size_t)2 * NBH * NT * 8192)
#define WS_VY ((size_t)3 * NBH * NT * 8192)
#define WS_NEED ((size_t)4 * NBH * NT * 8192)    // 16 MiB

// fp32 -> bf16 round-to-nearest-even
__device__ __forceinline__ short f2bf(float x) {
    unsigned u = __builtin_bit_cast(unsigned, x);
    u = (u + 0x7FFFu + ((u >> 16) & 1u)) >> 16;
    return (short)u;
}

// pack two f32 -> one dword of 2 bf16 (RNE)
__device__ __forceinline__ unsigned cvtpk(float lo, float hi) {
    unsigned d;
    asm("v_cvt_pk_bf16_f32 %0, %1, %2" : "=v"(d) : "v"(lo), "v"(hi));
    return d;
}

// XOR swizzle within a 128-byte row (guide G4) — K images only
__device__ __forceinline__ int swz(int row, int byteInRow) {
    return row * 128 + (byteInRow ^ ((row & 7) << 4));
}

// 16-byte async global->LDS copy
__device__ __forceinline__ void glds16(const void* g, void* l) {
    __builtin_amdgcn_global_load_lds(
        (const __attribute__((address_space(1))) unsigned*)g,
        (__attribute__((address_space(3))) unsigned*)l, 16, 0, 0);
}

// ------------- fused prepass: K row-major swizzled / V frag-major ------------
__global__ __launch_bounds__(256)
void prep_kv(const float* __restrict__ Kx, const float* __restrict__ Ky,
             const float* __restrict__ Vx, const float* __restrict__ Vy,
             char* __restrict__ ws)
{
    const int b = blockIdx.x;
    if (b < 1024) {
        const int tid  = b * 256 + threadIdx.x;
        const int dblk = tid & 7;
        const int s    = (tid >> 3) & 2047;
        const int bh   = tid >> 14;
        const size_t gi = ((size_t)bh * SS + s) * DD + dblk * 8;
        const int kt = s >> 6, row = s & 63;
        const size_t dst = (size_t)(bh * NT + kt) * 8192 + swz(row, dblk * 16);
        const float* px = Kx + gi;
        const float* py = Ky + gi;
        s16x8 a, bb;
#pragma unroll
        for (int i = 0; i < 8; ++i) { a[i] = f2bf(px[i]); bb[i] = f2bf(py[i]); }
        *(s16x8*)(ws + WS_KX + dst) = a;
        *(s16x8*)(ws + WS_KY + dst) = bb;
    } else {
        // V frag-major: elem e of lane (hi*32+l31) of frag (kt64,ks2,dt,ch) is
        // V[key = kt64*64 + ks2*32 + ch*16 + hi*8 + e][d = dt*32 + l31]
        const int tid  = (b - 1024) * 256 + threadIdx.x;
        const int d    = tid & 63;
        const int sblk = (tid >> 6) & 7;     // key octet within 64-key tile
        const int kt   = (tid >> 9) & 31;
        const int bh   = tid >> 14;
        const size_t gbase = ((size_t)bh * SS + kt * 64 + sblk * 8) * DD + d;
        s16x8 a, bb;
#pragma unroll
        for (int i = 0; i < 8; ++i) {
            a[i]  = f2bf(Vx[gbase + (size_t)i * DD]);
            bb[i] = f2bf(Vy[gbase + (size_t)i * DD]);
        }
        const int ks2 = sblk >> 2, ch = (sblk >> 1) & 1, hi = sblk & 1;
        const int dt = d >> 5, l31 = d & 31;
        const size_t dst = (size_t)bh * 262144
                         + (size_t)((((kt * 2 + ks2) * 2 + dt) * 2 + ch)) * 1024
                         + (size_t)(hi * 32 + l31) * 16;
        *(s16x8*)(ws + WS_VX + dst) = a;
        *(s16x8*)(ws + WS_VY + dst) = bb;
    }
}

// ------------------------------- main kernel ---------------------------------
// 32x32x16 MFMA, swapped QK^T, in-register softmax (no max; scores bounded).
// KBLK=128. 8 waves = qsub(2: 32 q-rows) x ks(4: 32-key quarter). No work
// duplication (R7 lesson); grid 512 x 512thr, K-only LDS dbuf 64KB -> 2
// blocks/CU = 16 waves/CU = 4/SIMD (R4/R8 were grid- or LDS-capped at 2/SIMD).
// V read directly from frag-major ws (L1/L2-resident; latency hidden by TLP).
__global__ __launch_bounds__(512, 4)
void attn_main(const float* __restrict__ Qx, const float* __restrict__ Qy,
               const char* __restrict__ ws, float* __restrict__ Out)
{
    extern __shared__ char lds[];

    const int t    = threadIdx.x;
    const int lane = t & 63;
    const int w    = t >> 6;      // 0..7
    const int qsub = w & 1;
    const int ks   = w >> 1;      // 0..3 (32-key quarter of 128-key tile)
    const int l31  = lane & 31;
    const int hi   = lane >> 5;   // 0/1

    // XCD-chunked swizzle (512 % 8 == 0, bijective): 64 consecutive per XCD
    int bid = blockIdx.x;
    bid = (bid & 7) * 64 + (bid >> 3);
    const int bh = bid >> 5;
    const int q0 = (bid & 31) * QBLK;
    const size_t base = (size_t)bh * SS * DD;

    // ---- Q B-frags: col q = lane&31, k = d = dc*16 + hi*8 + i
    const int qrow = q0 + qsub * 32 + l31;
    s16x8 qbx[4], qby[4];
#pragma unroll
    for (int dc = 0; dc < 4; ++dc) {
        const int d0 = dc * 16 + hi * 8;
        const float* qp = Qx + base + (size_t)qrow * DD + d0;
        const float* qq = Qy + base + (size_t)qrow * DD + d0;
        const float4 f0 = *(const float4*)qp;
        const float4 f1 = *(const float4*)(qp + 4);
        const float4 h0 = *(const float4*)qq;
        const float4 h1 = *(const float4*)(qq + 4);
        qbx[dc][0]=f2bf(f0.x); qbx[dc][1]=f2bf(f0.y); qbx[dc][2]=f2bf(f0.z); qbx[dc][3]=f2bf(f0.w);
        qbx[dc][4]=f2bf(f1.x); qbx[dc][5]=f2bf(f1.y); qbx[dc][6]=f2bf(f1.z); qbx[dc][7]=f2bf(f1.w);
        qby[dc][0]=f2bf(h0.x); qby[dc][1]=f2bf(h0.y); qby[dc][2]=f2bf(h0.z); qby[dc][3]=f2bf(h0.w);
        qby[dc][4]=f2bf(h1.x); qby[dc][5]=f2bf(h1.y); qby[dc][6]=f2bf(h1.z); qby[dc][7]=f2bf(h1.w);
    }

    f32x16 o1_0, o1_1, o2_0, o2_1;
#pragma unroll
    for (int j = 0; j < 16; ++j) { o1_0[j] = 0.f; o1_1[j] = 0.f; o2_0[j] = 0.f; o2_1[j] = 0.f; }
    float lsum = 0.f;

    const float SCL = 0.09016844005556021f;   // log2(e) / (2*sqrt(64))

    // stage 128-key tile kt_ (= 2 consecutive 64-key images, K only) into buf b_
    // layout: [KxA 8K | KxB 8K | KyA 8K | KyB 8K]
#define STAGE(kt_, b_)                                                             \
    do {                                                                           \
        const size_t imgA_ = (size_t)(bh * NT + (kt_) * 2) * 8192 + (size_t)t * 16;\
        char* dst_ = lds + (b_) * 32768 + t * 16;                                  \
        glds16(ws + WS_KX + imgA_,        dst_);                                   \
        glds16(ws + WS_KX + imgA_ + 8192, dst_ + 8192);                            \
        glds16(ws + WS_KY + imgA_,        dst_ + 16384);                           \
        glds16(ws + WS_KY + imgA_ + 8192, dst_ + 24576);                           \
    } while (0)

    STAGE(0, 0);
    __syncthreads();
    int cur = 0;

    const char* vxb = ws + WS_VX + (size_t)bh * 262144 + (size_t)lane * 16;
    const char* vyb = ws + WS_VY + (size_t)bh * 262144 + (size_t)lane * 16;

    // wave's K rows live in image half (ks>>1), within-image row (ks&1)*32+l31
    const int kimg = (ks >> 1) * 8192;
    const int krow = (ks & 1) * 32 + l31;

    for (int kt = 0; kt < NT2; ++kt) {
        if (kt + 1 < NT2) STAGE(kt + 1, cur ^ 1);

        const char* KL = lds + cur * 32768 + kimg;   // Kx at +0, Ky at +16384

        // ---- swapped scores: sc[key=crow(j,hi)][q=l31], keys = kt*128+ks*32..
        f32x16 sc;
#pragma unroll
        for (int j = 0; j < 16; ++j) sc[j] = 0.f;
        __builtin_amdgcn_s_setprio(1);
#pragma unroll
        for (int dc = 0; dc < 4; ++dc) {
            const int off = swz(krow, dc * 32 + hi * 16);
            const s16x8 ka = *(const s16x8*)(KL + off);
            const s16x8 kb = *(const s16x8*)(KL + 16384 + off);
            sc = __builtin_amdgcn_mfma_f32_32x32x16_bf16(ka, qbx[dc], sc, 0, 0, 0);
            sc = __builtin_amdgcn_mfma_f32_32x32x16_bf16(kb, qby[dc], sc, 0, 0, 0);
        }
        __builtin_amdgcn_s_setprio(0);

        // ---- V frag loads for dt0 (direct from ws; issue early to hide latency)
        const size_t vb = ((size_t)(kt * 4 + ks)) << 12;   // + dt*2048 + ch*1024
        const s16x8 vx00 = *(const s16x8*)(vxb + vb);
        const s16x8 vx01 = *(const s16x8*)(vxb + vb + 1024);
        const s16x8 vy00 = *(const s16x8*)(vyb + vb);
        const s16x8 vy01 = *(const s16x8*)(vyb + vb + 1024);

        // ---- softmax terms in place (|sc*SCL| <~ 30, fp32-safe without max)
        float s = 0.f;
#pragma unroll
        for (int j = 0; j < 16; ++j) {
            sc[j] = exp2f(sc[j] * SCL);
            s += sc[j];
        }
        lsum += s;

        // ---- P -> bf16 A-frags (verified shfl_xor redistribution)
        s16x8 pa[2];
#pragma unroll
        for (int ch = 0; ch < 2; ++ch) {
            const int b8 = ch * 8;
            const unsigned x0 = cvtpk(sc[b8 + 0], sc[b8 + 1]);
            const unsigned x1 = cvtpk(sc[b8 + 2], sc[b8 + 3]);
            const unsigned y0 = cvtpk(sc[b8 + 4], sc[b8 + 5]);
            const unsigned y1 = cvtpk(sc[b8 + 6], sc[b8 + 7]);
            const unsigned xs0 = (unsigned)__shfl_xor((int)x0, 32);
            const unsigned xs1 = (unsigned)__shfl_xor((int)x1, 32);
            const unsigned ys0 = (unsigned)__shfl_xor((int)y0, 32);
            const unsigned ys1 = (unsigned)__shfl_xor((int)y1, 32);
            i32x4 pw;
            pw[0] = (int)(hi ? ys0 : x0);
            pw[1] = (int)(hi ? ys1 : x1);
            pw[2] = (int)(hi ? y0 : xs0);
            pw[3] = (int)(hi ? y1 : xs1);
            pa[ch] = __builtin_bit_cast(s16x8, pw);
        }

        // ---- PV: out[q=crow][d=dt*32+l31] += P * V  (dt1 frags loaded JIT)
        __builtin_amdgcn_s_setprio(1);
        o1_0 = __builtin_amdgcn_mfma_f32_32x32x16_bf16(pa[0], vx00, o1_0, 0, 0, 0);
        o1_0 = __builtin_amdgcn_mfma_f32_32x32x16_bf16(pa[1], vx01, o1_0, 0, 0, 0);
        o2_0 = __builtin_amdgcn_mfma_f32_32x32x16_bf16(pa[0], vy00, o2_0, 0, 0, 0);
        o2_0 = __builtin_amdgcn_mfma_f32_32x32x16_bf16(pa[1], vy01, o2_0, 0, 0, 0);
        {
            const s16x8 vx10 = *(const s16x8*)(vxb + vb + 2048);
            const s16x8 vx11 = *(const s16x8*)(vxb + vb + 3072);
            const s16x8 vy10 = *(const s16x8*)(vyb + vb + 2048);
            const s16x8 vy11 = *(const s16x8*)(vyb + vb + 3072);
            o1_1 = __builtin_amdgcn_mfma_f32_32x32x16_bf16(pa[0], vx10, o1_1, 0, 0, 0);
            o1_1 = __builtin_amdgcn_mfma_f32_32x32x16_bf16(pa[1], vx11, o1_1, 0, 0, 0);
            o2_1 = __builtin_amdgcn_mfma_f32_32x32x16_bf16(pa[0], vy10, o2_1, 0, 0, 0);
            o2_1 = __builtin_amdgcn_mfma_f32_32x32x16_bf16(pa[1], vy11, o2_1, 0, 0, 0);
        }
        __builtin_amdgcn_s_setprio(0);

        __syncthreads();    // next K buffer staged (vmcnt drained); cur reads done
        cur ^= 1;
    }
#undef STAGE

    // ---- epilogue: combine 4 ks partials, per-q-row inverse, store (2 phases)
    const float lh = lsum + __shfl_xor(lsum, 32);   // 32-key-quarter sum, q=l31

    float* ex   = (float*)lds;                       // loop done: LDS reusable
    float* linv = (float*)(lds + 53248);             // 64 per-q-row inverses
    const int pid = (ks - 1) * 2 + qsub;             // 0..5 for ks=1..3
    const int exo = (pid * 64 + lane) * 33;          // 6*64*33*4B = 50688B < 52K
    float* O1 = Out;
    float* O2 = Out + (size_t)BB * HH * SS * DD;

    // phase 1: tensor X (+ lh)
    if (ks != 0) {
#pragma unroll
        for (int j = 0; j < 16; ++j) { ex[exo + j] = o1_0[j]; ex[exo + 16 + j] = o1_1[j]; }
        ex[exo + 32] = lh;
    }
    __syncthreads();
    if (ks == 0 && hi == 0) {
        float ltot = lh;
#pragma unroll
        for (int kk = 1; kk < 4; ++kk)
            ltot += ex[(((kk - 1) * 2 + qsub) * 64 + lane) * 33 + 32];
        linv[qsub * 32 + l31] = 1.0f / ltot;
    }
    __syncthreads();
    if (ks == 0) {
#pragma unroll
        for (int j = 0; j < 16; ++j) {
            const int qr = (j & 3) + 8 * (j >> 2) + 4 * hi;   // output q-row of reg j
            const float invj = linv[qsub * 32 + qr];
            float a0 = o1_0[j], a1 = o1_1[j];
#pragma unroll
            for (int kk = 1; kk < 4; ++kk) {
                const int eo = (((kk - 1) * 2 + qsub) * 64 + lane) * 33;
                a0 += ex[eo + j];
                a1 += ex[eo + 16 + j];
            }
            const size_t ob = base + (size_t)(q0 + qsub * 32 + qr) * DD + l31;
            O1[ob]      = a0 * invj;
            O1[ob + 32] = a1 * invj;
        }
    }
    __syncthreads();
    // phase 2: tensor Y
    if (ks != 0) {
#pragma unroll
        for (int j = 0; j < 16; ++j) { ex[exo + j] = o2_0[j]; ex[exo + 16 + j] = o2_1[j]; }
    }
    __syncthreads();
    if (ks == 0) {
#pragma unroll
        for (int j = 0; j < 16; ++j) {
            const int qr = (j & 3) + 8 * (j >> 2) + 4 * hi;
            const float invj = linv[qsub * 32 + qr];
            float a0 = o2_0[j], a1 = o2_1[j];
#pragma unroll
            for (int kk = 1; kk < 4; ++kk) {
                const int eo = (((kk - 1) * 2 + qsub) * 64 + lane) * 33;
                a0 += ex[eo + j];
                a1 += ex[eo + 16 + j];
            }
            const size_t ob = base + (size_t)(q0 + qsub * 32 + qr) * DD + l31;
            O2[ob]      = a0 * invj;
            O2[ob + 32] = a1 * invj;
        }
    }
}

// ===================== fallback (ws too small; validated R1 path) ============
__global__ __launch_bounds__(256, 2)
void attn_dual_fallback(const float* __restrict__ Qx, const float* __restrict__ Kx,
                        const float* __restrict__ Vx, const float* __restrict__ Qy,
                        const float* __restrict__ Ky, const float* __restrict__ Vy,
                        float* __restrict__ Out)
{
    __shared__ __attribute__((aligned(16))) char lds[40960];
    char* KxL  = lds;
    char* KyL  = lds + 8192;
    char* VtxL = lds + 16384;
    char* VtyL = lds + 24576;

    const int t    = threadIdx.x;
    const int lane = t & 63;
    const int w    = t >> 6;
    const int g    = lane >> 4;
    const int c    = lane & 15;
    char* PL = lds + 32768 + w * 2048;

    const int bid = blockIdx.x;
    const int bh  = bid >> 5;
    const int q0  = (bid & 31) * 64;
    const size_t base = (size_t)bh * SS * DD;

    const int qrowA = q0 + w * 16 + c;
    s16x8 qxf[2], qyf[2];
#pragma unroll
    for (int kk = 0; kk < 2; ++kk) {
        const int d0 = kk * 32 + g * 8;
        const float* qp = Qx + base + (size_t)qrowA * DD + d0;
        const float* qq = Qy + base + (size_t)qrowA * DD + d0;
#pragma unroll
        for (int i = 0; i < 8; ++i) { qxf[kk][i] = f2bf(qp[i]); qyf[kk][i] = f2bf(qq[i]); }
    }

    f32x4 o1[4], o2[4];
#pragma unroll
    for (int n = 0; n < 4; ++n) {
        o1[n] = (f32x4){0.f, 0.f, 0.f, 0.f};
        o2[n] = (f32x4){0.f, 0.f, 0.f, 0.f};
    }
    float m[4]    = {-1e30f, -1e30f, -1e30f, -1e30f};
    float lsum[4] = {0.f, 0.f, 0.f, 0.f};
    const float SCL = 0.09016844005556021f;

    for (int kt = 0; kt < SS / 64; ++kt) {
        __syncthreads();
#pragma unroll
        for (int j = 0; j < 4; ++j) {
            const int f   = t + 256 * j;
            const int row = f >> 4;
            const int c4  = f & 15;
            const size_t gi = base + (size_t)(kt * 64 + row) * DD + c4 * 4;
            const float4 kx = *(const float4*)(Kx + gi);
            const float4 ky = *(const float4*)(Ky + gi);
            const float4 vx = *(const float4*)(Vx + gi);
            const float4 vy = *(const float4*)(Vy + gi);
            s16x4 a; a[0]=f2bf(kx.x); a[1]=f2bf(kx.y); a[2]=f2bf(kx.z); a[3]=f2bf(kx.w);
            *(s16x4*)(KxL + swz(row, c4 * 8)) = a;
            s16x4 b; b[0]=f2bf(ky.x); b[1]=f2bf(ky.y); b[2]=f2bf(ky.z); b[3]=f2bf(ky.w);
            *(s16x4*)(KyL + swz(row, c4 * 8)) = b;
            const int d0 = c4 * 4;
            *(short*)(VtxL + swz(d0 + 0, row * 2)) = f2bf(vx.x);
            *(short*)(VtxL + swz(d0 + 1, row * 2)) = f2bf(vx.y);
            *(short*)(VtxL + swz(d0 + 2, row * 2)) = f2bf(vx.z);
            *(short*)(VtxL + swz(d0 + 3, row * 2)) = f2bf(vx.w);
            *(short*)(VtyL + swz(d0 + 0, row * 2)) = f2bf(vy.x);
            *(short*)(VtyL + swz(d0 + 1, row * 2)) = f2bf(vy.y);
            *(short*)(VtyL + swz(d0 + 2, row * 2)) = f2bf(vy.z);
            *(short*)(VtyL + swz(d0 + 3, row * 2)) = f2bf(vy.w);
        }
        __syncthreads();

        f32x4 sc[4];
#pragma unroll
        for (int n = 0; n < 4; ++n) {
            f32x4 acc = (f32x4){0.f, 0.f, 0.f, 0.f};
            const int keyrow = n * 16 + c;
#pragma unroll
            for (int kk = 0; kk < 2; ++kk) {
                const int off = swz(keyrow, (kk * 32 + g * 8) * 2);
                const s16x8 kxf = *(const s16x8*)(KxL + off);
                const s16x8 kyf = *(const s16x8*)(KyL + off);
                acc = __builtin_amdgcn_mfma_f32_16x16x32_bf16(qxf[kk], kxf, acc, 0, 0, 0);
                acc = __builtin_amdgcn_mfma_f32_16x16x32_bf16(qyf[kk], kyf, acc, 0, 0, 0);
            }
            sc[n] = acc;
        }

#pragma unroll
        for (int r = 0; r < 4; ++r) {
            float v0 = fmaxf(fmaxf(sc[0][r], sc[1][r]), fmaxf(sc[2][r], sc[3][r])) * SCL;
#pragma unroll
            for (int off = 1; off < 16; off <<= 1) v0 = fmaxf(v0, __shfl_xor(v0, off));
            const float mnew = fmaxf(m[r], v0);
            const float cr = exp2f(m[r] - mnew);
            m[r] = mnew;
            float srow = 0.f;
#pragma unroll
            for (int n = 0; n < 4; ++n) {
                const float pp = exp2f(sc[n][r] * SCL - mnew);
                srow += pp;
                *(short*)(PL + swz(g * 4 + r, (n * 16 + c) * 2)) = f2bf(pp);
            }
#pragma unroll
            for (int off = 1; off < 16; off <<= 1) srow += __shfl_xor(srow, off);
            lsum[r] = lsum[r] * cr + srow;
#pragma unroll
            for (int n = 0; n < 4; ++n) { o1[n][r] *= cr; o2[n][r] *= cr; }
        }

        s16x8 pf[2];
#pragma unroll
        for (int kk = 0; kk < 2; ++kk)
            pf[kk] = *(const s16x8*)(PL + swz(c, (kk * 32 + g * 8) * 2));
#pragma unroll
        for (int nd = 0; nd < 4; ++nd) {
            const int drow = nd * 16 + c;
#pragma unroll
            for (int kk = 0; kk < 2; ++kk) {
                const int off = swz(drow, (kk * 32 + g * 8) * 2);
                const s16x8 vxf = *(const s16x8*)(VtxL + off);
                const s16x8 vyf = *(const s16x8*)(VtyL + off);
                o1[nd] = __builtin_amdgcn_mfma_f32_16x16x32_bf16(pf[kk], vxf, o1[nd], 0, 0, 0);
                o2[nd] = __builtin_amdgcn_mfma_f32_16x16x32_bf16(pf[kk], vyf, o2[nd], 0, 0, 0);
            }
        }
    }

    float* O1 = Out;
    float* O2 = Out + (size_t)BB * HH * SS * DD;
#pragma unroll
    for (int r = 0; r < 4; ++r) {
        const float inv = 1.0f / lsum[r];
        const int qrow = q0 + w * 16 + g * 4 + r;
        const size_t ob = base + (size_t)qrow * DD + c;
#pragma unroll
        for (int nd = 0; nd < 4; ++nd) {
            O1[ob + nd * 16] = o1[nd][r] * inv;
            O2[ob + nd * 16] = o2[nd][r] * inv;
        }
    }
}

extern "C" void kernel_launch(void* const* d_in, const int* in_sizes, int n_in,
                              void* d_out, int out_size, void* d_ws, size_t ws_size,
                              hipStream_t stream) {
    const float* Qx = (const float*)d_in[0];
    const float* Kx = (const float*)d_in[1];
    const float* Vx = (const float*)d_in[2];
    const float* Qy = (const float*)d_in[3];
    const float* Ky = (const float*)d_in[4];
    const float* Vy = (const float*)d_in[5];
    float* Out = (float*)d_out;

    if (ws_size >= WS_NEED) {
        char* ws = (char*)d_ws;
        hipLaunchKernelGGL(prep_kv, dim3(2048), dim3(256), 0, stream,
                           Kx, Ky, Vx, Vy, ws);
        hipFuncSetAttribute((const void*)attn_main,
                            hipFuncAttributeMaxDynamicSharedMemorySize, 65536);
        hipLaunchKernelGGL(attn_main, dim3(NBH * (SS / QBLK)), dim3(512), 65536,
                           stream, Qx, Qy, (const char*)ws, Out);
    } else {
        hipLaunchKernelGGL(attn_dual_fallback, dim3(NBH * 32), dim3(256),
                           0, stream, Qx, Kx, Vx, Qy, Ky, Vy, Out);
    }
}

// Round 10
// 68.837 us; speedup vs baseline: 1.4816x; 1.3812x over previous
//
#include <hip/hip_runtime.h>
#include <hip/hip_bf16.h>

typedef __attribute__((ext_vector_type(4)))  float f32x4;
typedef __attribute__((ext_vector_type(16))) float f32x16;
typedef __attribute__((ext_vector_type(8)))  short s16x8;
typedef __attribute__((ext_vector_type(4)))  short s16x4;
typedef __attribute__((ext_vector_type(4)))  int   i32x4;

#define BB 2
#define HH 8
#define SS 2048
#define DD 64
#define QBLK 64
#define KBLK 64
#define NT   (SS / KBLK)      // 32
#define NBH  (BB * HH)        // 16

// ws layout: per-(bh,tile) 8KB pre-swizzled bf16 LDS images (K row-major,
// V transposed) — the R2/R7-verified format.
#define WS_KX 0
#define WS_KY ((size_t)NBH * NT * 8192)          // 4 MiB each
#define WS_VX ((size_t)2 * NBH * NT * 8192)
#define WS_VY ((size_t)3 * NBH * NT * 8192)
#define WS_NEED ((size_t)4 * NBH * NT * 8192)    // 16 MiB

// fp32 -> bf16 round-to-nearest-even
__device__ __forceinline__ short f2bf(float x) {
    unsigned u = __builtin_bit_cast(unsigned, x);
    u = (u + 0x7FFFu + ((u >> 16) & 1u)) >> 16;
    return (short)u;
}

// pack two f32 -> one dword of 2 bf16 (RNE)
__device__ __forceinline__ unsigned cvtpk(float lo, float hi) {
    unsigned d;
    asm("v_cvt_pk_bf16_f32 %0, %1, %2" : "=v"(d) : "v"(lo), "v"(hi));
    return d;
}

// XOR swizzle within a 128-byte row (guide G4)
__device__ __forceinline__ int swz(int row, int byteInRow) {
    return row * 128 + (byteInRow ^ ((row & 7) << 4));
}

// 16-byte async global->LDS copy
__device__ __forceinline__ void glds16(const void* g, void* l) {
    __builtin_amdgcn_global_load_lds(
        (const __attribute__((address_space(1))) unsigned*)g,
        (__attribute__((address_space(3))) unsigned*)l, 16, 0, 0);
}

// ------------- fused prepass (R7-verified): K row-major / V transposed -------
__global__ __launch_bounds__(256)
void prep_kv(const float* __restrict__ Kx, const float* __restrict__ Ky,
             const float* __restrict__ Vx, const float* __restrict__ Vy,
             char* __restrict__ ws)
{
    const int b = blockIdx.x;
    if (b < 1024) {
        const int tid  = b * 256 + threadIdx.x;
        const int dblk = tid & 7;
        const int s    = (tid >> 3) & 2047;
        const int bh   = tid >> 14;
        const size_t gi = ((size_t)bh * SS + s) * DD + dblk * 8;
        const int kt = s >> 6, row = s & 63;
        const size_t dst = (size_t)(bh * NT + kt) * 8192 + swz(row, dblk * 16);
        const float* px = Kx + gi;
        const float* py = Ky + gi;
        s16x8 a, bb;
#pragma unroll
        for (int i = 0; i < 8; ++i) { a[i] = f2bf(px[i]); bb[i] = f2bf(py[i]); }
        *(s16x8*)(ws + WS_KX + dst) = a;
        *(s16x8*)(ws + WS_KY + dst) = bb;
    } else {
        const int tid  = (b - 1024) * 256 + threadIdx.x;
        const int d    = tid & 63;
        const int sblk = (tid >> 6) & 7;
        const int kt   = (tid >> 9) & 31;
        const int bh   = tid >> 14;
        const size_t gbase = ((size_t)bh * SS + kt * 64 + sblk * 8) * DD + d;
        s16x8 a, bb;
#pragma unroll
        for (int i = 0; i < 8; ++i) {
            a[i]  = f2bf(Vx[gbase + (size_t)i * DD]);
            bb[i] = f2bf(Vy[gbase + (size_t)i * DD]);
        }
        const size_t dst = (size_t)(bh * NT + kt) * 8192 + swz(d, sblk * 16);
        *(s16x8*)(ws + WS_VX + dst) = a;
        *(s16x8*)(ws + WS_VY + dst) = bb;
    }
}

// ------------------------------- main kernel ---------------------------------
// R4's verified math/work exactly (32x32x16 swapped QK^T, in-register softmax,
// K+V in LDS dbuf, shfl P-redistribution), but the 8-wave lockstep block is
// split into independent 4-wave blocks: QBLK=64, waves = qsub(2) x ks(2),
// grid 512, LDS 64KB/block -> 2 blocks/CU (128/160KB). Same 8 waves/CU as R4;
// the two blocks' barrier drains overlap each other's compute (m114).
// R8/R9 lesson: V must stay in LDS (direct-from-L2 loads lengthen the chain).
__global__ __launch_bounds__(256, 2)
void attn_main(const float* __restrict__ Qx, const float* __restrict__ Qy,
               const char* __restrict__ ws, float* __restrict__ Out)
{
    extern __shared__ char lds[];

    const int t    = threadIdx.x;
    const int lane = t & 63;
    const int w    = t >> 6;      // 0..3
    const int qsub = w & 1;       // 32 q-rows
    const int ks   = w >> 1;      // 32-key half
    const int l31  = lane & 31;
    const int hi   = lane >> 5;   // 0/1

    // XCD-chunked swizzle (512 % 8 == 0, bijective): 64 consecutive per XCD
    int bid = blockIdx.x;
    bid = (bid & 7) * 64 + (bid >> 3);
    const int bh = bid >> 5;
    const int q0 = (bid & 31) * QBLK;
    const size_t base = (size_t)bh * SS * DD;

    // ---- Q B-frags: col q = lane&31, k = d = dc*16 + hi*8 + i
    const int qrow = q0 + qsub * 32 + l31;
    s16x8 qbx[4], qby[4];
#pragma unroll
    for (int dc = 0; dc < 4; ++dc) {
        const int d0 = dc * 16 + hi * 8;
        const float* qp = Qx + base + (size_t)qrow * DD + d0;
        const float* qq = Qy + base + (size_t)qrow * DD + d0;
        const float4 f0 = *(const float4*)qp;
        const float4 f1 = *(const float4*)(qp + 4);
        const float4 h0 = *(const float4*)qq;
        const float4 h1 = *(const float4*)(qq + 4);
        qbx[dc][0]=f2bf(f0.x); qbx[dc][1]=f2bf(f0.y); qbx[dc][2]=f2bf(f0.z); qbx[dc][3]=f2bf(f0.w);
        qbx[dc][4]=f2bf(f1.x); qbx[dc][5]=f2bf(f1.y); qbx[dc][6]=f2bf(f1.z); qbx[dc][7]=f2bf(f1.w);
        qby[dc][0]=f2bf(h0.x); qby[dc][1]=f2bf(h0.y); qby[dc][2]=f2bf(h0.z); qby[dc][3]=f2bf(h0.w);
        qby[dc][4]=f2bf(h1.x); qby[dc][5]=f2bf(h1.y); qby[dc][6]=f2bf(h1.z); qby[dc][7]=f2bf(h1.w);
    }

    f32x16 o1_0, o1_1, o2_0, o2_1;
#pragma unroll
    for (int j = 0; j < 16; ++j) { o1_0[j] = 0.f; o1_1[j] = 0.f; o2_0[j] = 0.f; o2_1[j] = 0.f; }
    float lsum = 0.f;

    const float SCL = 0.09016844005556021f;   // log2(e) / (2*sqrt(64))

    // stage tile kt_ into buffer b_ (8 x glds16 per thread; 256 thr x 16B x 8 = 32KB)
    // buffer layout: [Kx 8K | Ky 8K | Vtx 8K | Vty 8K]
#define STAGE(kt_, b_)                                                             \
    do {                                                                           \
        const size_t img_ = (size_t)(bh * NT + (kt_)) * 8192 + (size_t)t * 16;     \
        char* dst_ = lds + (b_) * 32768 + t * 16;                                  \
        glds16(ws + WS_KX + img_,        dst_);                                    \
        glds16(ws + WS_KX + img_ + 4096, dst_ + 4096);                             \
        glds16(ws + WS_KY + img_,        dst_ + 8192);                             \
        glds16(ws + WS_KY + img_ + 4096, dst_ + 12288);                            \
        glds16(ws + WS_VX + img_,        dst_ + 16384);                            \
        glds16(ws + WS_VX + img_ + 4096, dst_ + 20480);                            \
        glds16(ws + WS_VY + img_,        dst_ + 24576);                            \
        glds16(ws + WS_VY + img_ + 4096, dst_ + 28672);                            \
    } while (0)

    STAGE(0, 0);
    __syncthreads();
    int cur = 0;

    for (int kt = 0; kt < NT; ++kt) {
        if (kt + 1 < NT) STAGE(kt + 1, cur ^ 1);

        const char* KxL = lds + cur * 32768;
        const char* KyL = KxL + 8192;
        const char* VxL = KxL + 16384;
        const char* VyL = KxL + 24576;

        // ---- swapped scores: sc[key=crow(j,hi)][q=l31], keys = ks*32..+31
        f32x16 sc;
#pragma unroll
        for (int j = 0; j < 16; ++j) sc[j] = 0.f;
        __builtin_amdgcn_s_setprio(1);
#pragma unroll
        for (int dc = 0; dc < 4; ++dc) {
            const int off = swz(ks * 32 + l31, dc * 32 + hi * 16);
            const s16x8 ka = *(const s16x8*)(KxL + off);
            const s16x8 kb = *(const s16x8*)(KyL + off);
            sc = __builtin_amdgcn_mfma_f32_32x32x16_bf16(ka, qbx[dc], sc, 0, 0, 0);
            sc = __builtin_amdgcn_mfma_f32_32x32x16_bf16(kb, qby[dc], sc, 0, 0, 0);
        }
        __builtin_amdgcn_s_setprio(0);

        // ---- softmax terms in place (|sc*SCL| <~ 30, fp32-safe without max)
        float s = 0.f;
#pragma unroll
        for (int j = 0; j < 16; ++j) {
            sc[j] = exp2f(sc[j] * SCL);
            s += sc[j];
        }
        lsum += s;

        // ---- P -> bf16 A-frags (R4-verified shfl_xor redistribution)
        s16x8 pa[2];
#pragma unroll
        for (int ch = 0; ch < 2; ++ch) {
            const int b8 = ch * 8;
            const unsigned x0 = cvtpk(sc[b8 + 0], sc[b8 + 1]);
            const unsigned x1 = cvtpk(sc[b8 + 2], sc[b8 + 3]);
            const unsigned y0 = cvtpk(sc[b8 + 4], sc[b8 + 5]);
            const unsigned y1 = cvtpk(sc[b8 + 6], sc[b8 + 7]);
            const unsigned xs0 = (unsigned)__shfl_xor((int)x0, 32);
            const unsigned xs1 = (unsigned)__shfl_xor((int)x1, 32);
            const unsigned ys0 = (unsigned)__shfl_xor((int)y0, 32);
            const unsigned ys1 = (unsigned)__shfl_xor((int)y1, 32);
            i32x4 pw;
            pw[0] = (int)(hi ? ys0 : x0);
            pw[1] = (int)(hi ? ys1 : x1);
            pw[2] = (int)(hi ? y0 : xs0);
            pw[3] = (int)(hi ? y1 : xs1);
            pa[ch] = __builtin_bit_cast(s16x8, pw);
        }

        // ---- PV: out[q=crow][d=dt*32+l31] += P * V (both tensors, V from LDS)
        __builtin_amdgcn_s_setprio(1);
#pragma unroll
        for (int ch = 0; ch < 2; ++ch) {
            const int off0 = swz(0 * 32 + l31, ks * 64 + ch * 32 + hi * 16);
            const int off1 = swz(1 * 32 + l31, ks * 64 + ch * 32 + hi * 16);
            const s16x8 vx0 = *(const s16x8*)(VxL + off0);
            const s16x8 vx1 = *(const s16x8*)(VxL + off1);
            const s16x8 vy0 = *(const s16x8*)(VyL + off0);
            const s16x8 vy1 = *(const s16x8*)(VyL + off1);
            o1_0 = __builtin_amdgcn_mfma_f32_32x32x16_bf16(pa[ch], vx0, o1_0, 0, 0, 0);
            o1_1 = __builtin_amdgcn_mfma_f32_32x32x16_bf16(pa[ch], vx1, o1_1, 0, 0, 0);
            o2_0 = __builtin_amdgcn_mfma_f32_32x32x16_bf16(pa[ch], vy0, o2_0, 0, 0, 0);
            o2_1 = __builtin_amdgcn_mfma_f32_32x32x16_bf16(pa[ch], vy1, o2_1, 0, 0, 0);
        }
        __builtin_amdgcn_s_setprio(0);

        __syncthreads();    // next buffer staged (vmcnt drained); cur reads done
        cur ^= 1;
    }
#undef STAGE

    // ---- epilogue (R8-verified structure): combine ks partials, per-q-row inv
    const float lh = lsum + __shfl_xor(lsum, 32);   // 32-key-half sum for q=l31

    float* ex   = (float*)lds;                       // loop done: LDS reusable
    float* linv = (float*)(lds + 24576);             // 64 per-q-row inverses
    const int exo = (qsub * 64 + lane) * 33;         // stride 33: odd
    float* O1 = Out;
    float* O2 = Out + (size_t)BB * HH * SS * DD;

    // phase 1: tensor X (+ lh)
    if (ks == 1) {
#pragma unroll
        for (int j = 0; j < 16; ++j) { ex[exo + j] = o1_0[j]; ex[exo + 16 + j] = o1_1[j]; }
        ex[exo + 32] = lh;
    }
    __syncthreads();
    if (ks == 0 && hi == 0)
        linv[qsub * 32 + l31] = 1.0f / (lh + ex[exo + 32]);
    __syncthreads();
    if (ks == 0) {
#pragma unroll
        for (int j = 0; j < 16; ++j) {
            const int qr = (j & 3) + 8 * (j >> 2) + 4 * hi;   // output q-row of reg j
            const float invj = linv[qsub * 32 + qr];
            const size_t ob = base + (size_t)(q0 + qsub * 32 + qr) * DD + l31;
            O1[ob]      = (o1_0[j] + ex[exo + j])      * invj;
            O1[ob + 32] = (o1_1[j] + ex[exo + 16 + j]) * invj;
        }
    }
    __syncthreads();
    // phase 2: tensor Y
    if (ks == 1) {
#pragma unroll
        for (int j = 0; j < 16; ++j) { ex[exo + j] = o2_0[j]; ex[exo + 16 + j] = o2_1[j]; }
    }
    __syncthreads();
    if (ks == 0) {
#pragma unroll
        for (int j = 0; j < 16; ++j) {
            const int qr = (j & 3) + 8 * (j >> 2) + 4 * hi;
            const float invj = linv[qsub * 32 + qr];
            const size_t ob = base + (size_t)(q0 + qsub * 32 + qr) * DD + l31;
            O2[ob]      = (o2_0[j] + ex[exo + j])      * invj;
            O2[ob + 32] = (o2_1[j] + ex[exo + 16 + j]) * invj;
        }
    }
}

// ===================== fallback (ws too small; validated R1 path) ============
__global__ __launch_bounds__(256, 2)
void attn_dual_fallback(const float* __restrict__ Qx, const float* __restrict__ Kx,
                        const float* __restrict__ Vx, const float* __restrict__ Qy,
                        const float* __restrict__ Ky, const float* __restrict__ Vy,
                        float* __restrict__ Out)
{
    __shared__ __attribute__((aligned(16))) char lds[40960];
    char* KxL  = lds;
    char* KyL  = lds + 8192;
    char* VtxL = lds + 16384;
    char* VtyL = lds + 24576;

    const int t    = threadIdx.x;
    const int lane = t & 63;
    const int w    = t >> 6;
    const int g    = lane >> 4;
    const int c    = lane & 15;
    char* PL = lds + 32768 + w * 2048;

    const int bid = blockIdx.x;
    const int bh  = bid >> 5;
    const int q0  = (bid & 31) * 64;
    const size_t base = (size_t)bh * SS * DD;

    const int qrowA = q0 + w * 16 + c;
    s16x8 qxf[2], qyf[2];
#pragma unroll
    for (int kk = 0; kk < 2; ++kk) {
        const int d0 = kk * 32 + g * 8;
        const float* qp = Qx + base + (size_t)qrowA * DD + d0;
        const float* qq = Qy + base + (size_t)qrowA * DD + d0;
#pragma unroll
        for (int i = 0; i < 8; ++i) { qxf[kk][i] = f2bf(qp[i]); qyf[kk][i] = f2bf(qq[i]); }
    }

    f32x4 o1[4], o2[4];
#pragma unroll
    for (int n = 0; n < 4; ++n) {
        o1[n] = (f32x4){0.f, 0.f, 0.f, 0.f};
        o2[n] = (f32x4){0.f, 0.f, 0.f, 0.f};
    }
    float m[4]    = {-1e30f, -1e30f, -1e30f, -1e30f};
    float lsum[4] = {0.f, 0.f, 0.f, 0.f};
    const float SCL = 0.09016844005556021f;

    for (int kt = 0; kt < SS / 64; ++kt) {
        __syncthreads();
#pragma unroll
        for (int j = 0; j < 4; ++j) {
            const int f   = t + 256 * j;
            const int row = f >> 4;
            const int c4  = f & 15;
            const size_t gi = base + (size_t)(kt * 64 + row) * DD + c4 * 4;
            const float4 kx = *(const float4*)(Kx + gi);
            const float4 ky = *(const float4*)(Ky + gi);
            const float4 vx = *(const float4*)(Vx + gi);
            const float4 vy = *(const float4*)(Vy + gi);
            s16x4 a; a[0]=f2bf(kx.x); a[1]=f2bf(kx.y); a[2]=f2bf(kx.z); a[3]=f2bf(kx.w);
            *(s16x4*)(KxL + swz(row, c4 * 8)) = a;
            s16x4 b; b[0]=f2bf(ky.x); b[1]=f2bf(ky.y); b[2]=f2bf(ky.z); b[3]=f2bf(ky.w);
            *(s16x4*)(KyL + swz(row, c4 * 8)) = b;
            const int d0 = c4 * 4;
            *(short*)(VtxL + swz(d0 + 0, row * 2)) = f2bf(vx.x);
            *(short*)(VtxL + swz(d0 + 1, row * 2)) = f2bf(vx.y);
            *(short*)(VtxL + swz(d0 + 2, row * 2)) = f2bf(vx.z);
            *(short*)(VtxL + swz(d0 + 3, row * 2)) = f2bf(vx.w);
            *(short*)(VtyL + swz(d0 + 0, row * 2)) = f2bf(vy.x);
            *(short*)(VtyL + swz(d0 + 1, row * 2)) = f2bf(vy.y);
            *(short*)(VtyL + swz(d0 + 2, row * 2)) = f2bf(vy.z);
            *(short*)(VtyL + swz(d0 + 3, row * 2)) = f2bf(vy.w);
        }
        __syncthreads();

        f32x4 sc[4];
#pragma unroll
        for (int n = 0; n < 4; ++n) {
            f32x4 acc = (f32x4){0.f, 0.f, 0.f, 0.f};
            const int keyrow = n * 16 + c;
#pragma unroll
            for (int kk = 0; kk < 2; ++kk) {
                const int off = swz(keyrow, (kk * 32 + g * 8) * 2);
                const s16x8 kxf = *(const s16x8*)(KxL + off);
                const s16x8 kyf = *(const s16x8*)(KyL + off);
                acc = __builtin_amdgcn_mfma_f32_16x16x32_bf16(qxf[kk], kxf, acc, 0, 0, 0);
                acc = __builtin_amdgcn_mfma_f32_16x16x32_bf16(qyf[kk], kyf, acc, 0, 0, 0);
            }
            sc[n] = acc;
        }

#pragma unroll
        for (int r = 0; r < 4; ++r) {
            float v0 = fmaxf(fmaxf(sc[0][r], sc[1][r]), fmaxf(sc[2][r], sc[3][r])) * SCL;
#pragma unroll
            for (int off = 1; off < 16; off <<= 1) v0 = fmaxf(v0, __shfl_xor(v0, off));
            const float mnew = fmaxf(m[r], v0);
            const float cr = exp2f(m[r] - mnew);
            m[r] = mnew;
            float srow = 0.f;
#pragma unroll
            for (int n = 0; n < 4; ++n) {
                const float pp = exp2f(sc[n][r] * SCL - mnew);
                srow += pp;
                *(short*)(PL + swz(g * 4 + r, (n * 16 + c) * 2)) = f2bf(pp);
            }
#pragma unroll
            for (int off = 1; off < 16; off <<= 1) srow += __shfl_xor(srow, off);
            lsum[r] = lsum[r] * cr + srow;
#pragma unroll
            for (int n = 0; n < 4; ++n) { o1[n][r] *= cr; o2[n][r] *= cr; }
        }

        s16x8 pf[2];
#pragma unroll
        for (int kk = 0; kk < 2; ++kk)
            pf[kk] = *(const s16x8*)(PL + swz(c, (kk * 32 + g * 8) * 2));
#pragma unroll
        for (int nd = 0; nd < 4; ++nd) {
            const int drow = nd * 16 + c;
#pragma unroll
            for (int kk = 0; kk < 2; ++kk) {
                const int off = swz(drow, (kk * 32 + g * 8) * 2);
                const s16x8 vxf = *(const s16x8*)(VtxL + off);
                const s16x8 vyf = *(const s16x8*)(VtyL + off);
                o1[nd] = __builtin_amdgcn_mfma_f32_16x16x32_bf16(pf[kk], vxf, o1[nd], 0, 0, 0);
                o2[nd] = __builtin_amdgcn_mfma_f32_16x16x32_bf16(pf[kk], vyf, o2[nd], 0, 0, 0);
            }
        }
    }

    float* O1 = Out;
    float* O2 = Out + (size_t)BB * HH * SS * DD;
#pragma unroll
    for (int r = 0; r < 4; ++r) {
        const float inv = 1.0f / lsum[r];
        const int qrow = q0 + w * 16 + g * 4 + r;
        const size_t ob = base + (size_t)qrow * DD + c;
#pragma unroll
        for (int nd = 0; nd < 4; ++nd) {
            O1[ob + nd * 16] = o1[nd][r] * inv;
            O2[ob + nd * 16] = o2[nd][r] * inv;
        }
    }
}

extern "C" void kernel_launch(void* const* d_in, const int* in_sizes, int n_in,
                              void* d_out, int out_size, void* d_ws, size_t ws_size,
                              hipStream_t stream) {
    const float* Qx = (const float*)d_in[0];
    const float* Kx = (const float*)d_in[1];
    const float* Vx = (const float*)d_in[2];
    const float* Qy = (const float*)d_in[3];
    const float* Ky = (const float*)d_in[4];
    const float* Vy = (const float*)d_in[5];
    float* Out = (float*)d_out;

    if (ws_size >= WS_NEED) {
        char* ws = (char*)d_ws;
        hipLaunchKernelGGL(prep_kv, dim3(2048), dim3(256), 0, stream,
                           Kx, Ky, Vx, Vy, ws);
        hipFuncSetAttribute((const void*)attn_main,
                            hipFuncAttributeMaxDynamicSharedMemorySize, 65536);
        hipLaunchKernelGGL(attn_main, dim3(NBH * (SS / QBLK)), dim3(256), 65536,
                           stream, Qx, Qy, (const char*)ws, Out);
    } else {
        hipLaunchKernelGGL(attn_dual_fallback, dim3(NBH * 32), dim3(256),
                           0, stream, Qx, Kx, Vx, Qy, Ky, Vy, Out);
    }
}

// Round 11
// 65.846 us; speedup vs baseline: 1.5489x; 1.0454x over previous
//
#include <hip/hip_runtime.h>
#include <hip/hip_bf16.h>

typedef __attribute__((ext_vector_type(4)))  float f32x4;
typedef __attribute__((ext_vector_type(16))) float f32x16;
typedef __attribute__((ext_vector_type(8)))  short s16x8;
typedef __attribute__((ext_vector_type(4)))  short s16x4;
typedef __attribute__((ext_vector_type(4)))  int   i32x4;

#define BB 2
#define HH 8
#define SS 2048
#define DD 64
#define QBLK 64
#define KBLK 64
#define NT   (SS / KBLK)      // 32
#define NBH  (BB * HH)        // 16

// ws layout: per-(bh,tile) 8KB pre-swizzled bf16 LDS images (K row-major,
// V transposed) — the R2/R7-verified format.
#define WS_KX 0
#define WS_KY ((size_t)NBH * NT * 8192)          // 4 MiB each
#define WS_VX ((size_t)2 * NBH * NT * 8192)
#define WS_VY ((size_t)3 * NBH * NT * 8192)
#define WS_NEED ((size_t)4 * NBH * NT * 8192)    // 16 MiB

// fp32 -> bf16 round-to-nearest-even
__device__ __forceinline__ short f2bf(float x) {
    unsigned u = __builtin_bit_cast(unsigned, x);
    u = (u + 0x7FFFu + ((u >> 16) & 1u)) >> 16;
    return (short)u;
}

// pack two f32 -> one dword of 2 bf16 (RNE)
__device__ __forceinline__ unsigned cvtpk(float lo, float hi) {
    unsigned d;
    asm("v_cvt_pk_bf16_f32 %0, %1, %2" : "=v"(d) : "v"(lo), "v"(hi));
    return d;
}

// XOR swizzle within a 128-byte row (guide G4)
__device__ __forceinline__ int swz(int row, int byteInRow) {
    return row * 128 + (byteInRow ^ ((row & 7) << 4));
}

// 16-byte async global->LDS copy
__device__ __forceinline__ void glds16(const void* g, void* l) {
    __builtin_amdgcn_global_load_lds(
        (const __attribute__((address_space(1))) unsigned*)g,
        (__attribute__((address_space(3))) unsigned*)l, 16, 0, 0);
}

// ------------- fused prepass (R7-verified): K row-major / V transposed -------
__global__ __launch_bounds__(256)
void prep_kv(const float* __restrict__ Kx, const float* __restrict__ Ky,
             const float* __restrict__ Vx, const float* __restrict__ Vy,
             char* __restrict__ ws)
{
    const int b = blockIdx.x;
    if (b < 1024) {
        const int tid  = b * 256 + threadIdx.x;
        const int dblk = tid & 7;
        const int s    = (tid >> 3) & 2047;
        const int bh   = tid >> 14;
        const size_t gi = ((size_t)bh * SS + s) * DD + dblk * 8;
        const int kt = s >> 6, row = s & 63;
        const size_t dst = (size_t)(bh * NT + kt) * 8192 + swz(row, dblk * 16);
        const float* px = Kx + gi;
        const float* py = Ky + gi;
        s16x8 a, bb;
#pragma unroll
        for (int i = 0; i < 8; ++i) { a[i] = f2bf(px[i]); bb[i] = f2bf(py[i]); }
        *(s16x8*)(ws + WS_KX + dst) = a;
        *(s16x8*)(ws + WS_KY + dst) = bb;
    } else {
        const int tid  = (b - 1024) * 256 + threadIdx.x;
        const int d    = tid & 63;
        const int sblk = (tid >> 6) & 7;
        const int kt   = (tid >> 9) & 31;
        const int bh   = tid >> 14;
        const size_t gbase = ((size_t)bh * SS + kt * 64 + sblk * 8) * DD + d;
        s16x8 a, bb;
#pragma unroll
        for (int i = 0; i < 8; ++i) {
            a[i]  = f2bf(Vx[gbase + (size_t)i * DD]);
            bb[i] = f2bf(Vy[gbase + (size_t)i * DD]);
        }
        const size_t dst = (size_t)(bh * NT + kt) * 8192 + swz(d, sblk * 16);
        *(s16x8*)(ws + WS_VX + dst) = a;
        *(s16x8*)(ws + WS_VY + dst) = bb;
    }
}

// ------------------------------- main kernel ---------------------------------
// R10's verified math/layout with a 2-deep software pipeline (T15): iteration
// kt computes QK[kt] -> then PV[kt-1] (register-only: pa_prev x vr_prev) runs
// WITH softmax[kt] (VALU) — independent, so the scheduler fills MFMA bubbles.
// V-frags for tile kt are ds_read early and consumed next iteration.
// Accumulation order per output element is unchanged -> numerics identical.
__global__ __launch_bounds__(256, 2)
void attn_main(const float* __restrict__ Qx, const float* __restrict__ Qy,
               const char* __restrict__ ws, float* __restrict__ Out)
{
    extern __shared__ char lds[];

    const int t    = threadIdx.x;
    const int lane = t & 63;
    const int w    = t >> 6;      // 0..3
    const int qsub = w & 1;       // 32 q-rows
    const int ks   = w >> 1;      // 32-key half
    const int l31  = lane & 31;
    const int hi   = lane >> 5;   // 0/1

    // XCD-chunked swizzle (512 % 8 == 0, bijective)
    int bid = blockIdx.x;
    bid = (bid & 7) * 64 + (bid >> 3);
    const int bh = bid >> 5;
    const int q0 = (bid & 31) * QBLK;
    const size_t base = (size_t)bh * SS * DD;

    // ---- Q B-frags: col q = lane&31, k = d = dc*16 + hi*8 + i
    const int qrow = q0 + qsub * 32 + l31;
    s16x8 qbx[4], qby[4];
#pragma unroll
    for (int dc = 0; dc < 4; ++dc) {
        const int d0 = dc * 16 + hi * 8;
        const float* qp = Qx + base + (size_t)qrow * DD + d0;
        const float* qq = Qy + base + (size_t)qrow * DD + d0;
        const float4 f0 = *(const float4*)qp;
        const float4 f1 = *(const float4*)(qp + 4);
        const float4 h0 = *(const float4*)qq;
        const float4 h1 = *(const float4*)(qq + 4);
        qbx[dc][0]=f2bf(f0.x); qbx[dc][1]=f2bf(f0.y); qbx[dc][2]=f2bf(f0.z); qbx[dc][3]=f2bf(f0.w);
        qbx[dc][4]=f2bf(f1.x); qbx[dc][5]=f2bf(f1.y); qbx[dc][6]=f2bf(f1.z); qbx[dc][7]=f2bf(f1.w);
        qby[dc][0]=f2bf(h0.x); qby[dc][1]=f2bf(h0.y); qby[dc][2]=f2bf(h0.z); qby[dc][3]=f2bf(h0.w);
        qby[dc][4]=f2bf(h1.x); qby[dc][5]=f2bf(h1.y); qby[dc][6]=f2bf(h1.z); qby[dc][7]=f2bf(h1.w);
    }

    f32x16 o1_0, o1_1, o2_0, o2_1;
#pragma unroll
    for (int j = 0; j < 16; ++j) { o1_0[j] = 0.f; o1_1[j] = 0.f; o2_0[j] = 0.f; o2_1[j] = 0.f; }
    float lsum = 0.f;

    const float SCL = 0.09016844005556021f;   // log2(e) / (2*sqrt(64))

    // stage tile kt_ into buffer b_ (8 x glds16; buffer: Kx|Ky|Vtx|Vty 8KB each)
#define STAGE(kt_, b_)                                                             \
    do {                                                                           \
        const size_t img_ = (size_t)(bh * NT + (kt_)) * 8192 + (size_t)t * 16;     \
        char* dst_ = lds + (b_) * 32768 + t * 16;                                  \
        glds16(ws + WS_KX + img_,        dst_);                                    \
        glds16(ws + WS_KX + img_ + 4096, dst_ + 4096);                             \
        glds16(ws + WS_KY + img_,        dst_ + 8192);                             \
        glds16(ws + WS_KY + img_ + 4096, dst_ + 12288);                            \
        glds16(ws + WS_VX + img_,        dst_ + 16384);                            \
        glds16(ws + WS_VX + img_ + 4096, dst_ + 20480);                            \
        glds16(ws + WS_VY + img_,        dst_ + 24576);                            \
        glds16(ws + WS_VY + img_ + 4096, dst_ + 28672);                            \
    } while (0)

    // QK for current buffer -> sc
#define QK_BLOCK(KxL_, KyL_, sc_)                                                  \
    do {                                                                           \
        _Pragma("unroll")                                                          \
        for (int dc = 0; dc < 4; ++dc) {                                           \
            const int off = swz(ks * 32 + l31, dc * 32 + hi * 16);                 \
            const s16x8 ka = *(const s16x8*)((KxL_) + off);                        \
            const s16x8 kb = *(const s16x8*)((KyL_) + off);                        \
            sc_ = __builtin_amdgcn_mfma_f32_32x32x16_bf16(ka, qbx[dc], sc_, 0, 0, 0); \
            sc_ = __builtin_amdgcn_mfma_f32_32x32x16_bf16(kb, qby[dc], sc_, 0, 0, 0); \
        }                                                                          \
    } while (0)

    // V frag reads (8 x ds_read_b128) from current buffer into vr_[0..7]
#define V_READS(VxL_, VyL_, vr_)                                                   \
    do {                                                                           \
        _Pragma("unroll")                                                          \
        for (int ch = 0; ch < 2; ++ch) {                                           \
            const int off0 = swz(l31,      ks * 64 + ch * 32 + hi * 16);           \
            const int off1 = swz(32 + l31, ks * 64 + ch * 32 + hi * 16);           \
            vr_[ch * 4 + 0] = *(const s16x8*)((VxL_) + off0);                      \
            vr_[ch * 4 + 1] = *(const s16x8*)((VxL_) + off1);                      \
            vr_[ch * 4 + 2] = *(const s16x8*)((VyL_) + off0);                      \
            vr_[ch * 4 + 3] = *(const s16x8*)((VyL_) + off1);                      \
        }                                                                          \
    } while (0)

    // softmax in place + pa redistribution (verified shfl path)
#define SOFTMAX_PA(sc_, pa_)                                                       \
    do {                                                                           \
        float s_ = 0.f;                                                            \
        _Pragma("unroll")                                                          \
        for (int j = 0; j < 16; ++j) { sc_[j] = exp2f(sc_[j] * SCL); s_ += sc_[j]; } \
        lsum += s_;                                                                \
        _Pragma("unroll")                                                          \
        for (int ch = 0; ch < 2; ++ch) {                                           \
            const int b8 = ch * 8;                                                 \
            const unsigned x0 = cvtpk(sc_[b8 + 0], sc_[b8 + 1]);                   \
            const unsigned x1 = cvtpk(sc_[b8 + 2], sc_[b8 + 3]);                   \
            const unsigned y0 = cvtpk(sc_[b8 + 4], sc_[b8 + 5]);                   \
            const unsigned y1 = cvtpk(sc_[b8 + 6], sc_[b8 + 7]);                   \
            const unsigned xs0 = (unsigned)__shfl_xor((int)x0, 32);                \
            const unsigned xs1 = (unsigned)__shfl_xor((int)x1, 32);                \
            const unsigned ys0 = (unsigned)__shfl_xor((int)y0, 32);                \
            const unsigned ys1 = (unsigned)__shfl_xor((int)y1, 32);                \
            i32x4 pw;                                                              \
            pw[0] = (int)(hi ? ys0 : x0);                                          \
            pw[1] = (int)(hi ? ys1 : x1);                                          \
            pw[2] = (int)(hi ? y0 : xs0);                                          \
            pw[3] = (int)(hi ? y1 : xs1);                                          \
            pa_[ch] = __builtin_bit_cast(s16x8, pw);                               \
        }                                                                          \
    } while (0)

    // PV accumulate: o += pa_ x vr_  (register-only, 8 MFMA)
#define PV_BLOCK(pa_, vr_)                                                         \
    do {                                                                           \
        _Pragma("unroll")                                                          \
        for (int ch = 0; ch < 2; ++ch) {                                           \
            o1_0 = __builtin_amdgcn_mfma_f32_32x32x16_bf16(pa_[ch], vr_[ch*4+0], o1_0, 0, 0, 0); \
            o1_1 = __builtin_amdgcn_mfma_f32_32x32x16_bf16(pa_[ch], vr_[ch*4+1], o1_1, 0, 0, 0); \
            o2_0 = __builtin_amdgcn_mfma_f32_32x32x16_bf16(pa_[ch], vr_[ch*4+2], o2_0, 0, 0, 0); \
            o2_1 = __builtin_amdgcn_mfma_f32_32x32x16_bf16(pa_[ch], vr_[ch*4+3], o2_1, 0, 0, 0); \
        }                                                                          \
    } while (0)

    STAGE(0, 0);
    __syncthreads();

    // ---- prologue: tile 0 (QK + softmax + pa + V regs; PV deferred)
    s16x8 pa[2];
    s16x8 vr[8];
    {
        const char* KxL = lds;
        const char* KyL = KxL + 8192;
        const char* VxL = KxL + 16384;
        const char* VyL = KxL + 24576;
        f32x16 sc;
#pragma unroll
        for (int j = 0; j < 16; ++j) sc[j] = 0.f;
        __builtin_amdgcn_s_setprio(1);
        QK_BLOCK(KxL, KyL, sc);
        __builtin_amdgcn_s_setprio(0);
        V_READS(VxL, VyL, vr);
        SOFTMAX_PA(sc, pa);
    }
    STAGE(1, 1);
    __syncthreads();
    int cur = 1;

    // ---- steady state: QK[kt] ; V-reads[kt] ; PV[kt-1] || softmax[kt] ; rotate
#pragma unroll 2
    for (int kt = 1; kt < NT; ++kt) {
        if (kt + 1 < NT) STAGE(kt + 1, cur ^ 1);

        const char* KxL = lds + cur * 32768;
        const char* KyL = KxL + 8192;
        const char* VxL = KxL + 16384;
        const char* VyL = KxL + 24576;

        f32x16 sc;
#pragma unroll
        for (int j = 0; j < 16; ++j) sc[j] = 0.f;

        __builtin_amdgcn_s_setprio(1);
        QK_BLOCK(KxL, KyL, sc);

        s16x8 nvr[8];
        V_READS(VxL, VyL, nvr);

        // PV of previous tile (register-only) — independent of softmax below;
        // scheduler interleaves these MFMAs with the exp2/cvtpk VALU chain.
        PV_BLOCK(pa, vr);

        SOFTMAX_PA(sc, pa);
        __builtin_amdgcn_s_setprio(0);

#pragma unroll
        for (int i = 0; i < 8; ++i) vr[i] = nvr[i];

        __syncthreads();    // next buffer staged (vmcnt drained); cur reads done
        cur ^= 1;
    }

    // ---- final PV for tile NT-1
    __builtin_amdgcn_s_setprio(1);
    PV_BLOCK(pa, vr);
    __builtin_amdgcn_s_setprio(0);

#undef STAGE
#undef QK_BLOCK
#undef V_READS
#undef SOFTMAX_PA
#undef PV_BLOCK

    // ---- epilogue (R10-verified): combine ks partials, per-q-row inverse
    const float lh = lsum + __shfl_xor(lsum, 32);   // 32-key-half sum for q=l31

    __syncthreads();                                 // loop LDS now dead
    float* ex   = (float*)lds;
    float* linv = (float*)(lds + 24576);             // 64 per-q-row inverses
    const int exo = (qsub * 64 + lane) * 33;         // stride 33: odd
    float* O1 = Out;
    float* O2 = Out + (size_t)BB * HH * SS * DD;

    // phase 1: tensor X (+ lh)
    if (ks == 1) {
#pragma unroll
        for (int j = 0; j < 16; ++j) { ex[exo + j] = o1_0[j]; ex[exo + 16 + j] = o1_1[j]; }
        ex[exo + 32] = lh;
    }
    __syncthreads();
    if (ks == 0 && hi == 0)
        linv[qsub * 32 + l31] = 1.0f / (lh + ex[exo + 32]);
    __syncthreads();
    if (ks == 0) {
#pragma unroll
        for (int j = 0; j < 16; ++j) {
            const int qr = (j & 3) + 8 * (j >> 2) + 4 * hi;   // output q-row of reg j
            const float invj = linv[qsub * 32 + qr];
            const size_t ob = base + (size_t)(q0 + qsub * 32 + qr) * DD + l31;
            O1[ob]      = (o1_0[j] + ex[exo + j])      * invj;
            O1[ob + 32] = (o1_1[j] + ex[exo + 16 + j]) * invj;
        }
    }
    __syncthreads();
    // phase 2: tensor Y
    if (ks == 1) {
#pragma unroll
        for (int j = 0; j < 16; ++j) { ex[exo + j] = o2_0[j]; ex[exo + 16 + j] = o2_1[j]; }
    }
    __syncthreads();
    if (ks == 0) {
#pragma unroll
        for (int j = 0; j < 16; ++j) {
            const int qr = (j & 3) + 8 * (j >> 2) + 4 * hi;
            const float invj = linv[qsub * 32 + qr];
            const size_t ob = base + (size_t)(q0 + qsub * 32 + qr) * DD + l31;
            O2[ob]      = (o2_0[j] + ex[exo + j])      * invj;
            O2[ob + 32] = (o2_1[j] + ex[exo + 16 + j]) * invj;
        }
    }
}

// ===================== fallback (ws too small; validated R1 path) ============
__global__ __launch_bounds__(256, 2)
void attn_dual_fallback(const float* __restrict__ Qx, const float* __restrict__ Kx,
                        const float* __restrict__ Vx, const float* __restrict__ Qy,
                        const float* __restrict__ Ky, const float* __restrict__ Vy,
                        float* __restrict__ Out)
{
    __shared__ __attribute__((aligned(16))) char lds[40960];
    char* KxL  = lds;
    char* KyL  = lds + 8192;
    char* VtxL = lds + 16384;
    char* VtyL = lds + 24576;

    const int t    = threadIdx.x;
    const int lane = t & 63;
    const int w    = t >> 6;
    const int g    = lane >> 4;
    const int c    = lane & 15;
    char* PL = lds + 32768 + w * 2048;

    const int bid = blockIdx.x;
    const int bh  = bid >> 5;
    const int q0  = (bid & 31) * 64;
    const size_t base = (size_t)bh * SS * DD;

    const int qrowA = q0 + w * 16 + c;
    s16x8 qxf[2], qyf[2];
#pragma unroll
    for (int kk = 0; kk < 2; ++kk) {
        const int d0 = kk * 32 + g * 8;
        const float* qp = Qx + base + (size_t)qrowA * DD + d0;
        const float* qq = Qy + base + (size_t)qrowA * DD + d0;
#pragma unroll
        for (int i = 0; i < 8; ++i) { qxf[kk][i] = f2bf(qp[i]); qyf[kk][i] = f2bf(qq[i]); }
    }

    f32x4 o1[4], o2[4];
#pragma unroll
    for (int n = 0; n < 4; ++n) {
        o1[n] = (f32x4){0.f, 0.f, 0.f, 0.f};
        o2[n] = (f32x4){0.f, 0.f, 0.f, 0.f};
    }
    float m[4]    = {-1e30f, -1e30f, -1e30f, -1e30f};
    float lsum[4] = {0.f, 0.f, 0.f, 0.f};
    const float SCL = 0.09016844005556021f;

    for (int kt = 0; kt < SS / 64; ++kt) {
        __syncthreads();
#pragma unroll
        for (int j = 0; j < 4; ++j) {
            const int f   = t + 256 * j;
            const int row = f >> 4;
            const int c4  = f & 15;
            const size_t gi = base + (size_t)(kt * 64 + row) * DD + c4 * 4;
            const float4 kx = *(const float4*)(Kx + gi);
            const float4 ky = *(const float4*)(Ky + gi);
            const float4 vx = *(const float4*)(Vx + gi);
            const float4 vy = *(const float4*)(Vy + gi);
            s16x4 a; a[0]=f2bf(kx.x); a[1]=f2bf(kx.y); a[2]=f2bf(kx.z); a[3]=f2bf(kx.w);
            *(s16x4*)(KxL + swz(row, c4 * 8)) = a;
            s16x4 b; b[0]=f2bf(ky.x); b[1]=f2bf(ky.y); b[2]=f2bf(ky.z); b[3]=f2bf(ky.w);
            *(s16x4*)(KyL + swz(row, c4 * 8)) = b;
            const int d0 = c4 * 4;
            *(short*)(VtxL + swz(d0 + 0, row * 2)) = f2bf(vx.x);
            *(short*)(VtxL + swz(d0 + 1, row * 2)) = f2bf(vx.y);
            *(short*)(VtxL + swz(d0 + 2, row * 2)) = f2bf(vx.z);
            *(short*)(VtxL + swz(d0 + 3, row * 2)) = f2bf(vx.w);
            *(short*)(VtyL + swz(d0 + 0, row * 2)) = f2bf(vy.x);
            *(short*)(VtyL + swz(d0 + 1, row * 2)) = f2bf(vy.y);
            *(short*)(VtyL + swz(d0 + 2, row * 2)) = f2bf(vy.z);
            *(short*)(VtyL + swz(d0 + 3, row * 2)) = f2bf(vy.w);
        }
        __syncthreads();

        f32x4 sc[4];
#pragma unroll
        for (int n = 0; n < 4; ++n) {
            f32x4 acc = (f32x4){0.f, 0.f, 0.f, 0.f};
            const int keyrow = n * 16 + c;
#pragma unroll
            for (int kk = 0; kk < 2; ++kk) {
                const int off = swz(keyrow, (kk * 32 + g * 8) * 2);
                const s16x8 kxf = *(const s16x8*)(KxL + off);
                const s16x8 kyf = *(const s16x8*)(KyL + off);
                acc = __builtin_amdgcn_mfma_f32_16x16x32_bf16(qxf[kk], kxf, acc, 0, 0, 0);
                acc = __builtin_amdgcn_mfma_f32_16x16x32_bf16(qyf[kk], kyf, acc, 0, 0, 0);
            }
            sc[n] = acc;
        }

#pragma unroll
        for (int r = 0; r < 4; ++r) {
            float v0 = fmaxf(fmaxf(sc[0][r], sc[1][r]), fmaxf(sc[2][r], sc[3][r])) * SCL;
#pragma unroll
            for (int off = 1; off < 16; off <<= 1) v0 = fmaxf(v0, __shfl_xor(v0, off));
            const float mnew = fmaxf(m[r], v0);
            const float cr = exp2f(m[r] - mnew);
            m[r] = mnew;
            float srow = 0.f;
#pragma unroll
            for (int n = 0; n < 4; ++n) {
                const float pp = exp2f(sc[n][r] * SCL - mnew);
                srow += pp;
                *(short*)(PL + swz(g * 4 + r, (n * 16 + c) * 2)) = f2bf(pp);
            }
#pragma unroll
            for (int off = 1; off < 16; off <<= 1) srow += __shfl_xor(srow, off);
            lsum[r] = lsum[r] * cr + srow;
#pragma unroll
            for (int n = 0; n < 4; ++n) { o1[n][r] *= cr; o2[n][r] *= cr; }
        }

        s16x8 pf[2];
#pragma unroll
        for (int kk = 0; kk < 2; ++kk)
            pf[kk] = *(const s16x8*)(PL + swz(c, (kk * 32 + g * 8) * 2));
#pragma unroll
        for (int nd = 0; nd < 4; ++nd) {
            const int drow = nd * 16 + c;
#pragma unroll
            for (int kk = 0; kk < 2; ++kk) {
                const int off = swz(drow, (kk * 32 + g * 8) * 2);
                const s16x8 vxf = *(const s16x8*)(VtxL + off);
                const s16x8 vyf = *(const s16x8*)(VtyL + off);
                o1[nd] = __builtin_amdgcn_mfma_f32_16x16x32_bf16(pf[kk], vxf, o1[nd], 0, 0, 0);
                o2[nd] = __builtin_amdgcn_mfma_f32_16x16x32_bf16(pf[kk], vyf, o2[nd], 0, 0, 0);
            }
        }
    }

    float* O1 = Out;
    float* O2 = Out + (size_t)BB * HH * SS * DD;
#pragma unroll
    for (int r = 0; r < 4; ++r) {
        const float inv = 1.0f / lsum[r];
        const int qrow = q0 + w * 16 + g * 4 + r;
        const size_t ob = base + (size_t)qrow * DD + c;
#pragma unroll
        for (int nd = 0; nd < 4; ++nd) {
            O1[ob + nd * 16] = o1[nd][r] * inv;
            O2[ob + nd * 16] = o2[nd][r] * inv;
        }
    }
}

extern "C" void kernel_launch(void* const* d_in, const int* in_sizes, int n_in,
                              void* d_out, int out_size, void* d_ws, size_t ws_size,
                              hipStream_t stream) {
    const float* Qx = (const float*)d_in[0];
    const float* Kx = (const float*)d_in[1];
    const float* Vx = (const float*)d_in[2];
    const float* Qy = (const float*)d_in[3];
    const float* Ky = (const float*)d_in[4];
    const float* Vy = (const float*)d_in[5];
    float* Out = (float*)d_out;

    if (ws_size >= WS_NEED) {
        char* ws = (char*)d_ws;
        hipLaunchKernelGGL(prep_kv, dim3(2048), dim3(256), 0, stream,
                           Kx, Ky, Vx, Vy, ws);
        hipFuncSetAttribute((const void*)attn_main,
                            hipFuncAttributeMaxDynamicSharedMemorySize, 65536);
        hipLaunchKernelGGL(attn_main, dim3(NBH * (SS / QBLK)), dim3(256), 65536,
                           stream, Qx, Qy, (const char*)ws, Out);
    } else {
        hipLaunchKernelGGL(attn_dual_fallback, dim3(NBH * 32), dim3(256),
                           0, stream, Qx, Kx, Vx, Qy, Ky, Vy, Out);
    }
}